// Round 1
// baseline (132.245 us; speedup 1.0000x reference)
//
#include <hip/hip_runtime.h>
#include <float.h>
#include <math.h>

// ---------------------------------------------------------------------------
// DRR via Siddon ray casting.  NX=NY=NZ=192, H=W=192, SDR=300, DELX=DELY=2,
// SPACING=1, BAM=1, B=2, N_SUB=18432.
// Pipeline (4 dispatches, was 9):
//   memset(out) -> reduce (block partials, NO atomics) ->
//   prep (ONE block: final-reduce + LDS-bitmask compact -> tile-ordered list)
//   -> ray (exact per-step midpoint voxel pick; reciprocal-mul alpha updates;
//   16 alpha-chunks per ray).
//
// Perf history:
//  - r1 reduce=146us / r4 reduce=64us were SAME-CACHE-LINE atomic
//    serialization; two-stage reduction with plain stores fixed it.
//  - 127.9us plateau: top-5 rocprof dispatches were all harness fills ->
//    every kernel <43us; ~60us of wall time was dispatch gaps across 9
//    launches.  This version fuses reduce_final+mark+count+scan+emit (and
//    the mark memset) into one single-block prep kernel.  List ordering is
//    byte-identical to the old emit (row-major within 8x8 tile), so
//    ray_kernel's memory behavior is unchanged.
// ---------------------------------------------------------------------------

#define NDIM   192
#define HW     (NDIM * NDIM)          // 36864
#define NSUB   (HW / 2)               // 18432
#define NTILE  576                    // 8x8 detector tiles (24x24 of them)
#define NBATCH 2
#define NCHUNK 16
#define NVOX   (NDIM * NDIM * NDIM)   // 7077888
#define SDRF   300.0f
#define RBLK   1728                   // reduce blocks: 1728*256*4 f4 == NVOX/4

// ws layout (bytes):
//   [0..12)                      final {smin, rmin, rmax}
//   [16 .. 16+4*NSUB)            list (tile-ordered selected pixels)
//   [16+4*NSUB .. +4*3*RBLK)     block partials smin[RBLK],rmin[RBLK],rmax[RBLK]
#define WS_LIST_OFF 16
#define WS_PART_OFF (WS_LIST_OFF + 4 * NSUB)

// --------------------------- reduction stage 1 -----------------------------
// soft_min over (-800, 350]; rmin/rmax over v > -800 (BAM==1 -> identity).
// Each block stores 3 partials to DISTINCT slots (no atomics).
__global__ __launch_bounds__(256) void reduce_kernel(
    const float* __restrict__ vol, float* __restrict__ parts) {
    const int tid = blockIdx.x * 256 + threadIdx.x;
    const float4* __restrict__ v4 = (const float4*)vol;
    const int S = RBLK * 256;         // 442368

    float4 r0 = v4[tid + 0 * S];
    float4 r1 = v4[tid + 1 * S];
    float4 r2 = v4[tid + 2 * S];
    float4 r3 = v4[tid + 3 * S];

    float smin = FLT_MAX, rmin = FLT_MAX, rmax = -FLT_MAX;
    float4 rr[4] = {r0, r1, r2, r3};
#pragma unroll
    for (int k = 0; k < 4; ++k) {
        float xs[4] = {rr[k].x, rr[k].y, rr[k].z, rr[k].w};
#pragma unroll
        for (int j = 0; j < 4; ++j) {
            float x = xs[j];
            bool in = (x > -800.0f);
            rmin = fminf(rmin, in ? x : FLT_MAX);
            rmax = fmaxf(rmax, in ? x : -FLT_MAX);
            smin = fminf(smin, (in && x <= 350.0f) ? x : FLT_MAX);
        }
    }
#pragma unroll
    for (int off = 32; off > 0; off >>= 1) {
        smin = fminf(smin, __shfl_down(smin, off));
        rmin = fminf(rmin, __shfl_down(rmin, off));
        rmax = fmaxf(rmax, __shfl_down(rmax, off));
    }
    __shared__ float sm[4], rm[4], rx[4];
    int w = threadIdx.x >> 6;
    if ((threadIdx.x & 63) == 0) { sm[w] = smin; rm[w] = rmin; rx[w] = rmax; }
    __syncthreads();
    if (threadIdx.x == 0) {
        parts[blockIdx.x] =
            fminf(fminf(sm[0], sm[1]), fminf(sm[2], sm[3]));
        parts[RBLK + blockIdx.x] =
            fminf(fminf(rm[0], rm[1]), fminf(rm[2], rm[3]));
        parts[2 * RBLK + blockIdx.x] =
            fmaxf(fmaxf(rx[0], rx[1]), fmaxf(rx[2], rx[3]));
    }
}

// --------------------------- fused prep (ONE block) ------------------------
// Phase 1: final reduce of 3x1728 partials -> ws[0..2]
// Phase 2: zero LDS bitmask (36864 bits = 1152 u32)
// Phase 3: set bits from subsample_idx (LDS atomicOr)
// Phase 4: per-tile counts.  Tile t: ti=t/24, tj=t%24.  Pixel (pi, tj*8+j)
//          has bitmask BYTE index pi*24+tj, bit j  (byte-aligned columns!)
// Phase 5: Hillis-Steele exclusive scan over 576 counts
// Phase 6: emit list, row-major within tile == identical order to old emit.
__global__ __launch_bounds__(1024) void prep_kernel(
    const float* __restrict__ parts, const int* __restrict__ sidx,
    float* __restrict__ ws, int* __restrict__ list) {
    __shared__ unsigned int bits[HW / 32];   // 1152 u32 = 4608 B
    __shared__ int cnts[NTILE];
    __shared__ float red0[16], red1[16], red2[16];

    const int tid = threadIdx.x;

    // ---- phase 1: final reduce (strided over 1728 partials) ----
    float smin = FLT_MAX, rmin = FLT_MAX, rmax = -FLT_MAX;
    for (int i = tid; i < RBLK; i += 1024) {
        smin = fminf(smin, parts[i]);
        rmin = fminf(rmin, parts[RBLK + i]);
        rmax = fmaxf(rmax, parts[2 * RBLK + i]);
    }
#pragma unroll
    for (int off = 32; off > 0; off >>= 1) {
        smin = fminf(smin, __shfl_down(smin, off));
        rmin = fminf(rmin, __shfl_down(rmin, off));
        rmax = fmaxf(rmax, __shfl_down(rmax, off));
    }
    int w = tid >> 6;                  // 16 waves
    if ((tid & 63) == 0) { red0[w] = smin; red1[w] = rmin; red2[w] = rmax; }

    // ---- phase 2: zero bitmask (also covers the red[] sync) ----
    for (int i = tid; i < HW / 32; i += 1024) bits[i] = 0u;
    __syncthreads();
    if (tid == 0) {
        float a = FLT_MAX, b = FLT_MAX, c = -FLT_MAX;
#pragma unroll
        for (int k = 0; k < 16; ++k) {
            a = fminf(a, red0[k]);
            b = fminf(b, red1[k]);
            c = fmaxf(c, red2[k]);
        }
        ws[0] = a; ws[1] = b; ws[2] = c;
    }

    // ---- phase 3: set bits ----
    for (int i = tid; i < NSUB; i += 1024) {
        int p = sidx[i];
        atomicOr(&bits[p >> 5], 1u << (p & 31));
    }
    __syncthreads();

    // ---- phase 4: per-tile counts via byte popcounts ----
    const unsigned char* bb = (const unsigned char*)bits;
    int myc = 0;
    int ti = tid / 24, tj = tid % 24;  // valid when tid < NTILE
    if (tid < NTILE) {
#pragma unroll
        for (int r = 0; r < 8; ++r)
            myc += __popc((int)bb[(ti * 8 + r) * 24 + tj]);
        cnts[tid] = myc;
    }
    __syncthreads();

    // ---- phase 5: inclusive scan -> exclusive offset in register ----
    for (int off = 1; off < NTILE; off <<= 1) {
        int v = 0, u = 0;
        if (tid < NTILE) {
            v = cnts[tid];
            if (tid >= off) u = cnts[tid - off];
        }
        __syncthreads();
        if (tid < NTILE) cnts[tid] = v + u;
        __syncthreads();
    }

    // ---- phase 6: emit (row-major within tile; same order as old emit) ----
    if (tid < NTILE) {
        int o = cnts[tid] - myc;       // exclusive prefix
#pragma unroll
        for (int r = 0; r < 8; ++r) {
            int pibase = (ti * 8 + r) * NDIM + tj * 8;
            unsigned int m = (unsigned int)bb[(ti * 8 + r) * 24 + tj];
            while (m) {
                int j = __ffs(m) - 1;
                m &= m - 1u;
                list[o++] = pibase + j;
            }
        }
    }
}

// --------------------------- axis iterator init ----------------------------
// First plane index (walking toward increasing alpha) whose
// alpha = (i - s)/d is STRICTLY greater than a_lo.  Exact divides (once).
__device__ __forceinline__ void init_axis(float s, float d, float a_lo,
                                          int& i, int& st, float& na) {
    if (d > 0.0f) {
        st = 1;
        float f = s + a_lo * d;
        int ii = (int)floorf(f) + 1;
        ii = max(0, min(ii, NDIM + 1));
        while (ii <= NDIM && ((float)ii - s) / d <= a_lo) ++ii;
        while (ii > 0 && ((float)(ii - 1) - s) / d > a_lo) --ii;
        i  = ii;
        na = (ii <= NDIM) ? ((float)ii - s) / d : FLT_MAX;
    } else {
        st = -1;
        float f = s + a_lo * d;
        int ii = (int)ceilf(f) - 1;
        ii = max(-1, min(ii, NDIM));
        while (ii >= 0 && ((float)ii - s) / d <= a_lo) --ii;
        while (ii < NDIM && ((float)(ii + 1) - s) / d > a_lo) ++ii;
        i  = ii;
        na = (ii >= 0) ? ((float)ii - s) / d : FLT_MAX;
    }
}

// --------------------------- ray kernel ------------------------------------
// Wave = 64 consecutive list entries (compact detector patches).
// grid = (NSUB/256, NCHUNK, NBATCH), block = 256 (4 waves).
// Per step: exact midpoint voxel pick (matches reference); alpha crossings
// recomputed from integer plane index via reciprocal-mul (no drift).
__global__ __launch_bounds__(256) void ray_kernel(
    const float* __restrict__ vol, const float* __restrict__ rot,
    const float* __restrict__ trans, const float* __restrict__ wsc,
    const int* __restrict__ list, float* __restrict__ out) {
    const int n = blockIdx.x * 256 + threadIdx.x;
    const int c = blockIdx.y;
    const int b = blockIdx.z;

    const int p  = list[n];
    const int pi = p / NDIM;
    const int pj = p % NDIM;

    // density normalization constants
    float smin = wsc[0];
    float rmin = wsc[1];
    float rmax = wsc[2];
    float dmin = fminf(smin, rmin);
    float dmax = fmaxf(smin, rmax);
    float scale = 1.0f / (dmax - dmin);

    // rotation R = Rz(r0) @ Ry(r1) @ Rx(r2)
    float rz = rot[b * 3 + 0], ry = rot[b * 3 + 1], rx = rot[b * 3 + 2];
    float cz = cosf(rz), sz = sinf(rz);
    float cy = cosf(ry), sy = sinf(ry);
    float cx = cosf(rx), sx = sinf(rx);
    float R00 = cz * cy;
    float R01 = cz * sy * sx - sz * cx;
    float R02 = sz * sx + cz * sy * cx;
    float R10 = sz * cy;
    float R11 = cz * cx + sz * sy * sx;
    float R12 = sz * sy * cx - cz * sx;
    float R20 = -sy;
    float R21 = cy * sx;
    float R22 = cy * cx;
    float tx = trans[b * 3 + 0] + 96.0f;
    float ty = trans[b * 3 + 1] + 96.0f;
    float tz = trans[b * 3 + 2] + 96.0f;

    float srcx = R02 * SDRF + tx;
    float srcy = R12 * SDRF + ty;
    float srcz = R22 * SDRF + tz;
    float gx = ((float)pj - 95.5f) * 2.0f;
    float gy = ((float)pi - 95.5f) * 2.0f;
    float tgx = R00 * gx + R01 * gy + R02 * (-SDRF) + tx;
    float tgy = R10 * gx + R11 * gy + R12 * (-SDRF) + ty;
    float tgz = R20 * gx + R21 * gy + R22 * (-SDRF) + tz;

    float sdx = tgx - srcx, sdy = tgy - srcy, sdz = tgz - srcz;
    float dsx = (sdx == 0.0f) ? 1e-9f : sdx;
    float dsy = (sdy == 0.0f) ? 1e-9f : sdy;
    float dsz = (sdz == 0.0f) ? 1e-9f : sdz;

    float af0 = (0.0f - srcx) / dsx, al0 = (192.0f - srcx) / dsx;
    float af1 = (0.0f - srcy) / dsy, al1 = (192.0f - srcy) / dsy;
    float af2 = (0.0f - srcz) / dsz, al2 = (192.0f - srcz) / dsz;
    float amin = fmaxf(fmaxf(fminf(af0, al0), fminf(af1, al1)), fminf(af2, al2));
    amin = fmaxf(amin, 0.0f);
    float amax = fminf(fminf(fmaxf(af0, al0), fmaxf(af1, al1)), fmaxf(af2, al2));
    amax = fminf(amax, 1.0f);
    amax = fmaxf(amax, amin);
    float ray_len = sqrtf(sdx * sdx + sdy * sdy + sdz * sdz);

    // alpha sub-interval of this chunk
    float span = amax - amin;
    float a_lo = amin + span * ((float)c / (float)NCHUNK);
    float a_hi = (c == NCHUNK - 1) ? amax
                                   : amin + span * ((float)(c + 1) / (float)NCHUNK);

    int i0, i1, i2, st0, st1, st2;
    float na0, na1, na2;
    init_axis(srcx, dsx, a_lo, i0, st0, na0);
    init_axis(srcy, dsy, a_lo, i1, st1, na1);
    init_axis(srcz, dsz, a_lo, i2, st2, na2);

    // reciprocals (IEEE divide once per thread) and float-index trackers
    float r0 = 1.0f / dsx, r1 = 1.0f / dsy, r2 = 1.0f / dsz;
    float fi0 = (float)i0, fi1 = (float)i1, fi2 = (float)i2;
    float fs0 = (float)st0, fs1 = (float)st1, fs2 = (float)st2;

    float cur = a_lo;
    float acc = 0.0f;                 // sum of step * raw_density
    while (true) {
        float an  = fminf(fminf(na0, na1), na2);
        bool fin  = !(an < a_hi);
        float a2  = fin ? a_hi : an;
        float mid = 0.5f * (cur + a2);
        float px = fmaf(mid, sdx, srcx);
        float py = fmaf(mid, sdy, srcy);
        float pz = fmaf(mid, sdz, srcz);
        // truncation == floor after the >=0 clamp (see reference clip)
        int ix = min(max((int)px, 0), NDIM - 1);
        int iy = min(max((int)py, 0), NDIM - 1);
        int iz = min(max((int)pz, 0), NDIM - 1);
        int addr = (NDIM - 1) * HW - ix * HW + iy * NDIM + iz;  // flip axis 0
        float v  = vol[addr];
        float dv = (v <= -800.0f) ? smin : v;
        acc = fmaf(a2 - cur, dv, acc);
        if (fin) break;
        cur = a2;
        bool c0 = (na0 == an), c1 = (na1 == an), c2 = (na2 == an);
        // recompute crossing alpha from integer index: no drift accumulation
        float nf0 = fi0 + fs0, nf1 = fi1 + fs1, nf2 = fi2 + fs2;
        float nn0 = (nf0 - srcx) * r0;
        float nn1 = (nf1 - srcy) * r1;
        float nn2 = (nf2 - srcz) * r2;
        fi0 = c0 ? nf0 : fi0;  na0 = c0 ? nn0 : na0;
        fi1 = c1 ? nf1 : fi1;  na1 = c1 ? nn1 : na1;
        fi2 = c2 ? nf2 : fi2;  na2 = c2 ? nn2 : na2;
    }
    // sum step*(dv - dmin)*scale == scale*(acc - dmin*(a_hi - a_lo))
    float res = (acc - dmin * (a_hi - a_lo)) * scale * ray_len;
    atomicAdd(&out[b * HW + p], res);
}

// --------------------------- launch ----------------------------------------
extern "C" void kernel_launch(void* const* d_in, const int* in_sizes, int n_in,
                              void* d_out, int out_size, void* d_ws,
                              size_t ws_size, hipStream_t stream) {
    const float* vol   = (const float*)d_in[0];
    const float* rot   = (const float*)d_in[1];
    const float* trans = (const float*)d_in[2];
    const int*   sidx  = (const int*)d_in[3];
    float* out = (float*)d_out;

    float* wsf   = (float*)d_ws;
    int*   list  = (int*)((unsigned char*)d_ws + WS_LIST_OFF);
    float* parts = (float*)((unsigned char*)d_ws + WS_PART_OFF);

    hipMemsetAsync(d_out, 0, (size_t)out_size * sizeof(float), stream);

    reduce_kernel<<<RBLK, 256, 0, stream>>>(vol, parts);
    prep_kernel<<<1, 1024, 0, stream>>>(parts, sidx, wsf, list);
    dim3 rgrid(NSUB / 256, NCHUNK, NBATCH);
    ray_kernel<<<rgrid, 256, 0, stream>>>(vol, rot, trans, wsf, list, out);
}

// Round 3
// 131.670 us; speedup vs baseline: 1.0044x; 1.0044x over previous
//
#include <hip/hip_runtime.h>
#include <float.h>
#include <math.h>

// ---------------------------------------------------------------------------
// DRR via Siddon ray casting.  NX=NY=NZ=192, H=W=192, SDR=300, DELX=DELY=2,
// SPACING=1, BAM=1, B=2, N_SUB=18432.
// Pipeline (4 dispatches):
//   memset(out) -> reduce (block partials, NO atomics) ->
//   prep (ONE block: final-reduce + LDS-bitmask compact -> tile-ordered list)
//   -> ray (exact per-step midpoint voxel pick; reciprocal-mul alpha updates;
//   16 alpha-chunks per ray; XCD-pinned chunk mapping).
//
// Perf history:
//  - r1 reduce=146us / r4 reduce=64us: same-cache-line atomic serialization;
//    fixed by two-stage reduction with plain stores.
//  - 127.9us plateau: top-5 rocprof dispatches all ~43us harness poison
//    fills (2x 256MiB per iteration ~ 86us fixed floor).  Fusing 9->4
//    dispatches was NEUTRAL (132 vs 128) -> dispatch gaps are sub-us; the
//    remaining lever is ray_kernel (~30-35us by subtraction).
//  - This version: XCD-pinned chunk mapping.  Previously blockIdx.y (alpha
//    chunk) round-robined over 8 XCDs, so every XCD's private 4MiB L2
//    streamed the whole ~34MB traversed volume (29x reuse it can't hold) ->
//    ~1GB of gathers served from L3.  Now ray launches as a 1D grid and
//    derives (bx, chunk, batch) from the raw dispatch index with
//    XCD = L%8 (measured round-robin), giving XCD x chunks {2x,2x+1} for
//    both batches: working set/XCD ~ 4.2MB ~ L2 size.  Per-thread math is
//    bit-identical; only scheduling locality changes.
//  - R2 submission failed to COMPILE: decode temp `r2` collided with
//    reciprocal `float r2`.  Renamed decode temps (rq/rq2); no other change.
// ---------------------------------------------------------------------------

#define NDIM   192
#define HW     (NDIM * NDIM)          // 36864
#define NSUB   (HW / 2)               // 18432
#define NTILE  576                    // 8x8 detector tiles (24x24 of them)
#define NBATCH 2
#define NCHUNK 16
#define NVOX   (NDIM * NDIM * NDIM)   // 7077888
#define SDRF   300.0f
#define RBLK   1728                   // reduce blocks: 1728*256*4 f4 == NVOX/4
#define NBLKX  (NSUB / 256)           // 72 ray blocks per (chunk,batch)

// ws layout (bytes):
//   [0..12)                      final {smin, rmin, rmax}
//   [16 .. 16+4*NSUB)            list (tile-ordered selected pixels)
//   [16+4*NSUB .. +4*3*RBLK)     block partials smin[RBLK],rmin[RBLK],rmax[RBLK]
#define WS_LIST_OFF 16
#define WS_PART_OFF (WS_LIST_OFF + 4 * NSUB)

// --------------------------- reduction stage 1 -----------------------------
// soft_min over (-800, 350]; rmin/rmax over v > -800 (BAM==1 -> identity).
// Each block stores 3 partials to DISTINCT slots (no atomics).
__global__ __launch_bounds__(256) void reduce_kernel(
    const float* __restrict__ vol, float* __restrict__ parts) {
    const int tid = blockIdx.x * 256 + threadIdx.x;
    const float4* __restrict__ v4 = (const float4*)vol;
    const int S = RBLK * 256;         // 442368

    float4 r0 = v4[tid + 0 * S];
    float4 r1 = v4[tid + 1 * S];
    float4 r2 = v4[tid + 2 * S];
    float4 r3 = v4[tid + 3 * S];

    float smin = FLT_MAX, rmin = FLT_MAX, rmax = -FLT_MAX;
    float4 rr[4] = {r0, r1, r2, r3};
#pragma unroll
    for (int k = 0; k < 4; ++k) {
        float xs[4] = {rr[k].x, rr[k].y, rr[k].z, rr[k].w};
#pragma unroll
        for (int j = 0; j < 4; ++j) {
            float x = xs[j];
            bool in = (x > -800.0f);
            rmin = fminf(rmin, in ? x : FLT_MAX);
            rmax = fmaxf(rmax, in ? x : -FLT_MAX);
            smin = fminf(smin, (in && x <= 350.0f) ? x : FLT_MAX);
        }
    }
#pragma unroll
    for (int off = 32; off > 0; off >>= 1) {
        smin = fminf(smin, __shfl_down(smin, off));
        rmin = fminf(rmin, __shfl_down(rmin, off));
        rmax = fmaxf(rmax, __shfl_down(rmax, off));
    }
    __shared__ float sm[4], rm[4], rx[4];
    int w = threadIdx.x >> 6;
    if ((threadIdx.x & 63) == 0) { sm[w] = smin; rm[w] = rmin; rx[w] = rmax; }
    __syncthreads();
    if (threadIdx.x == 0) {
        parts[blockIdx.x] =
            fminf(fminf(sm[0], sm[1]), fminf(sm[2], sm[3]));
        parts[RBLK + blockIdx.x] =
            fminf(fminf(rm[0], rm[1]), fminf(rm[2], rm[3]));
        parts[2 * RBLK + blockIdx.x] =
            fmaxf(fmaxf(rx[0], rx[1]), fmaxf(rx[2], rx[3]));
    }
}

// --------------------------- fused prep (ONE block) ------------------------
// Phase 1: final reduce of 3x1728 partials -> ws[0..2]
// Phase 2: zero LDS bitmask (36864 bits = 1152 u32)
// Phase 3: set bits from subsample_idx (LDS atomicOr)
// Phase 4: per-tile counts.  Tile t: ti=t/24, tj=t%24.  Pixel (pi, tj*8+j)
//          has bitmask BYTE index pi*24+tj, bit j  (byte-aligned columns!)
// Phase 5: Hillis-Steele exclusive scan over 576 counts
// Phase 6: emit list, row-major within tile == identical order to old emit.
__global__ __launch_bounds__(1024) void prep_kernel(
    const float* __restrict__ parts, const int* __restrict__ sidx,
    float* __restrict__ ws, int* __restrict__ list) {
    __shared__ unsigned int bits[HW / 32];   // 1152 u32 = 4608 B
    __shared__ int cnts[NTILE];
    __shared__ float red0[16], red1[16], red2[16];

    const int tid = threadIdx.x;

    // ---- phase 1: final reduce (strided over 1728 partials) ----
    float smin = FLT_MAX, rmin = FLT_MAX, rmax = -FLT_MAX;
    for (int i = tid; i < RBLK; i += 1024) {
        smin = fminf(smin, parts[i]);
        rmin = fminf(rmin, parts[RBLK + i]);
        rmax = fmaxf(rmax, parts[2 * RBLK + i]);
    }
#pragma unroll
    for (int off = 32; off > 0; off >>= 1) {
        smin = fminf(smin, __shfl_down(smin, off));
        rmin = fminf(rmin, __shfl_down(rmin, off));
        rmax = fmaxf(rmax, __shfl_down(rmax, off));
    }
    int w = tid >> 6;                  // 16 waves
    if ((tid & 63) == 0) { red0[w] = smin; red1[w] = rmin; red2[w] = rmax; }

    // ---- phase 2: zero bitmask (also covers the red[] sync) ----
    for (int i = tid; i < HW / 32; i += 1024) bits[i] = 0u;
    __syncthreads();
    if (tid == 0) {
        float a = FLT_MAX, b = FLT_MAX, c = -FLT_MAX;
#pragma unroll
        for (int k = 0; k < 16; ++k) {
            a = fminf(a, red0[k]);
            b = fminf(b, red1[k]);
            c = fmaxf(c, red2[k]);
        }
        ws[0] = a; ws[1] = b; ws[2] = c;
    }

    // ---- phase 3: set bits ----
    for (int i = tid; i < NSUB; i += 1024) {
        int p = sidx[i];
        atomicOr(&bits[p >> 5], 1u << (p & 31));
    }
    __syncthreads();

    // ---- phase 4: per-tile counts via byte popcounts ----
    const unsigned char* bb = (const unsigned char*)bits;
    int myc = 0;
    int ti = tid / 24, tj = tid % 24;  // valid when tid < NTILE
    if (tid < NTILE) {
#pragma unroll
        for (int r = 0; r < 8; ++r)
            myc += __popc((int)bb[(ti * 8 + r) * 24 + tj]);
        cnts[tid] = myc;
    }
    __syncthreads();

    // ---- phase 5: inclusive scan -> exclusive offset in register ----
    for (int off = 1; off < NTILE; off <<= 1) {
        int v = 0, u = 0;
        if (tid < NTILE) {
            v = cnts[tid];
            if (tid >= off) u = cnts[tid - off];
        }
        __syncthreads();
        if (tid < NTILE) cnts[tid] = v + u;
        __syncthreads();
    }

    // ---- phase 6: emit (row-major within tile; same order as old emit) ----
    if (tid < NTILE) {
        int o = cnts[tid] - myc;       // exclusive prefix
#pragma unroll
        for (int r = 0; r < 8; ++r) {
            int pibase = (ti * 8 + r) * NDIM + tj * 8;
            unsigned int m = (unsigned int)bb[(ti * 8 + r) * 24 + tj];
            while (m) {
                int j = __ffs(m) - 1;
                m &= m - 1u;
                list[o++] = pibase + j;
            }
        }
    }
}

// --------------------------- axis iterator init ----------------------------
// First plane index (walking toward increasing alpha) whose
// alpha = (i - s)/d is STRICTLY greater than a_lo.  Exact divides (once).
__device__ __forceinline__ void init_axis(float s, float d, float a_lo,
                                          int& i, int& st, float& na) {
    if (d > 0.0f) {
        st = 1;
        float f = s + a_lo * d;
        int ii = (int)floorf(f) + 1;
        ii = max(0, min(ii, NDIM + 1));
        while (ii <= NDIM && ((float)ii - s) / d <= a_lo) ++ii;
        while (ii > 0 && ((float)(ii - 1) - s) / d > a_lo) --ii;
        i  = ii;
        na = (ii <= NDIM) ? ((float)ii - s) / d : FLT_MAX;
    } else {
        st = -1;
        float f = s + a_lo * d;
        int ii = (int)ceilf(f) - 1;
        ii = max(-1, min(ii, NDIM));
        while (ii >= 0 && ((float)ii - s) / d <= a_lo) --ii;
        while (ii < NDIM && ((float)(ii + 1) - s) / d > a_lo) ++ii;
        i  = ii;
        na = (ii >= 0) ? ((float)ii - s) / d : FLT_MAX;
    }
}

// --------------------------- ray kernel ------------------------------------
// 1D grid of NBLKX*NCHUNK*NBATCH blocks.  (bx, chunk, batch) derived from the
// raw dispatch index so that XCD = L%8 (measured round-robin) pins chunk
// pairs {2x, 2x+1} to XCD x -> each XCD's L2 holds its own ~4.2MB alpha-slab
// working set instead of streaming the whole traversed volume from L3.
// Wave = 64 consecutive list entries (compact detector patches).
// Per step: exact midpoint voxel pick (matches reference); alpha crossings
// recomputed from integer plane index via reciprocal-mul (no drift).
__global__ __launch_bounds__(256) void ray_kernel(
    const float* __restrict__ vol, const float* __restrict__ rot,
    const float* __restrict__ trans, const float* __restrict__ wsc,
    const int* __restrict__ list, float* __restrict__ out) {
    const int L   = blockIdx.x;       // 0 .. NBLKX*NCHUNK*NBATCH-1
    const int X   = L & 7;            // presumed XCD (round-robin)
    const int rq  = L >> 3;           // 0 .. 287
    const int c   = 2 * X + (rq & 1); // chunk: XCD x owns {2x, 2x+1}
    const int rq2 = rq >> 1;          // 0 .. 143
    const int bx  = rq2 % NBLKX;
    const int b   = rq2 / NBLKX;

    const int n = bx * 256 + threadIdx.x;
    const int p  = list[n];
    const int pi = p / NDIM;
    const int pj = p % NDIM;

    // density normalization constants
    float smin = wsc[0];
    float rmin = wsc[1];
    float rmax = wsc[2];
    float dmin = fminf(smin, rmin);
    float dmax = fmaxf(smin, rmax);
    float scale = 1.0f / (dmax - dmin);

    // rotation R = Rz(r0) @ Ry(r1) @ Rx(r2)
    float rz = rot[b * 3 + 0], ry = rot[b * 3 + 1], rx = rot[b * 3 + 2];
    float cz = cosf(rz), sz = sinf(rz);
    float cy = cosf(ry), sy = sinf(ry);
    float cx = cosf(rx), sx = sinf(rx);
    float R00 = cz * cy;
    float R01 = cz * sy * sx - sz * cx;
    float R02 = sz * sx + cz * sy * cx;
    float R10 = sz * cy;
    float R11 = cz * cx + sz * sy * sx;
    float R12 = sz * sy * cx - cz * sx;
    float R20 = -sy;
    float R21 = cy * sx;
    float R22 = cy * cx;
    float tx = trans[b * 3 + 0] + 96.0f;
    float ty = trans[b * 3 + 1] + 96.0f;
    float tz = trans[b * 3 + 2] + 96.0f;

    float srcx = R02 * SDRF + tx;
    float srcy = R12 * SDRF + ty;
    float srcz = R22 * SDRF + tz;
    float gx = ((float)pj - 95.5f) * 2.0f;
    float gy = ((float)pi - 95.5f) * 2.0f;
    float tgx = R00 * gx + R01 * gy + R02 * (-SDRF) + tx;
    float tgy = R10 * gx + R11 * gy + R12 * (-SDRF) + ty;
    float tgz = R20 * gx + R21 * gy + R22 * (-SDRF) + tz;

    float sdx = tgx - srcx, sdy = tgy - srcy, sdz = tgz - srcz;
    float dsx = (sdx == 0.0f) ? 1e-9f : sdx;
    float dsy = (sdy == 0.0f) ? 1e-9f : sdy;
    float dsz = (sdz == 0.0f) ? 1e-9f : sdz;

    float af0 = (0.0f - srcx) / dsx, al0 = (192.0f - srcx) / dsx;
    float af1 = (0.0f - srcy) / dsy, al1 = (192.0f - srcy) / dsy;
    float af2 = (0.0f - srcz) / dsz, al2 = (192.0f - srcz) / dsz;
    float amin = fmaxf(fmaxf(fminf(af0, al0), fminf(af1, al1)), fminf(af2, al2));
    amin = fmaxf(amin, 0.0f);
    float amax = fminf(fminf(fmaxf(af0, al0), fmaxf(af1, al1)), fmaxf(af2, al2));
    amax = fminf(amax, 1.0f);
    amax = fmaxf(amax, amin);
    float ray_len = sqrtf(sdx * sdx + sdy * sdy + sdz * sdz);

    // alpha sub-interval of this chunk
    float span = amax - amin;
    float a_lo = amin + span * ((float)c / (float)NCHUNK);
    float a_hi = (c == NCHUNK - 1) ? amax
                                   : amin + span * ((float)(c + 1) / (float)NCHUNK);

    int i0, i1, i2, st0, st1, st2;
    float na0, na1, na2;
    init_axis(srcx, dsx, a_lo, i0, st0, na0);
    init_axis(srcy, dsy, a_lo, i1, st1, na1);
    init_axis(srcz, dsz, a_lo, i2, st2, na2);

    // reciprocals (IEEE divide once per thread) and float-index trackers
    float r0 = 1.0f / dsx, r1 = 1.0f / dsy, r2 = 1.0f / dsz;
    float fi0 = (float)i0, fi1 = (float)i1, fi2 = (float)i2;
    float fs0 = (float)st0, fs1 = (float)st1, fs2 = (float)st2;

    float cur = a_lo;
    float acc = 0.0f;                 // sum of step * raw_density
    while (true) {
        float an  = fminf(fminf(na0, na1), na2);
        bool fin  = !(an < a_hi);
        float a2  = fin ? a_hi : an;
        float mid = 0.5f * (cur + a2);
        float px = fmaf(mid, sdx, srcx);
        float py = fmaf(mid, sdy, srcy);
        float pz = fmaf(mid, sdz, srcz);
        // truncation == floor after the >=0 clamp (see reference clip)
        int ix = min(max((int)px, 0), NDIM - 1);
        int iy = min(max((int)py, 0), NDIM - 1);
        int iz = min(max((int)pz, 0), NDIM - 1);
        int addr = (NDIM - 1) * HW - ix * HW + iy * NDIM + iz;  // flip axis 0
        float v  = vol[addr];
        float dv = (v <= -800.0f) ? smin : v;
        acc = fmaf(a2 - cur, dv, acc);
        if (fin) break;
        cur = a2;
        bool c0 = (na0 == an), c1 = (na1 == an), c2 = (na2 == an);
        // recompute crossing alpha from integer index: no drift accumulation
        float nf0 = fi0 + fs0, nf1 = fi1 + fs1, nf2 = fi2 + fs2;
        float nn0 = (nf0 - srcx) * r0;
        float nn1 = (nf1 - srcy) * r1;
        float nn2 = (nf2 - srcz) * r2;
        fi0 = c0 ? nf0 : fi0;  na0 = c0 ? nn0 : na0;
        fi1 = c1 ? nf1 : fi1;  na1 = c1 ? nn1 : na1;
        fi2 = c2 ? nf2 : fi2;  na2 = c2 ? nn2 : na2;
    }
    // sum step*(dv - dmin)*scale == scale*(acc - dmin*(a_hi - a_lo))
    float res = (acc - dmin * (a_hi - a_lo)) * scale * ray_len;
    atomicAdd(&out[b * HW + p], res);
}

// --------------------------- launch ----------------------------------------
extern "C" void kernel_launch(void* const* d_in, const int* in_sizes, int n_in,
                              void* d_out, int out_size, void* d_ws,
                              size_t ws_size, hipStream_t stream) {
    const float* vol   = (const float*)d_in[0];
    const float* rot   = (const float*)d_in[1];
    const float* trans = (const float*)d_in[2];
    const int*   sidx  = (const int*)d_in[3];
    float* out = (float*)d_out;

    float* wsf   = (float*)d_ws;
    int*   list  = (int*)((unsigned char*)d_ws + WS_LIST_OFF);
    float* parts = (float*)((unsigned char*)d_ws + WS_PART_OFF);

    hipMemsetAsync(d_out, 0, (size_t)out_size * sizeof(float), stream);

    reduce_kernel<<<RBLK, 256, 0, stream>>>(vol, parts);
    prep_kernel<<<1, 1024, 0, stream>>>(parts, sidx, wsf, list);
    ray_kernel<<<NBLKX * NCHUNK * NBATCH, 256, 0, stream>>>(
        vol, rot, trans, wsf, list, out);
}

// Round 4
// 125.731 us; speedup vs baseline: 1.0518x; 1.0472x over previous
//
#include <hip/hip_runtime.h>
#include <float.h>
#include <math.h>

// ---------------------------------------------------------------------------
// DRR via Siddon ray casting.  NX=NY=NZ=192, H=W=192, SDR=300, DELX=DELY=2,
// SPACING=1, BAM=1, B=2, N_SUB=18432.
// Pipeline (4 dispatches):
//   memset(out) -> reduce (block partials, NO atomics) ->
//   prep (ONE block: final-reduce + LDS-bitmask compact -> tile-ordered list)
//   -> ray (fixed-trip, branch-free Siddon walk with a DEPTH-4 software
//   pipeline of gathers; 16 alpha-chunks per ray).
//
// Perf history:
//  - r1 reduce=146us / r4 reduce=64us: same-cache-line atomic serialization;
//    fixed by two-stage reduction with plain stores.
//  - 127.9us plateau: 2x ~43us harness poison fills are a fixed ~86us floor.
//    Fusing 9->4 dispatches: NEUTRAL (gaps are sub-us).
//  - XCD-pinned chunk mapping: FALSIFIED.  ray=43.9us with pinning (was
//    <=41.6 without); hbm_gbps=1264 (16% peak) -> not BW-bound.  Reverted.
//  - ray counters (R3): VALUBusy=40%, Occ=47%, FETCH=49MB -> latency-bound:
//    one scattered gather per step, acc-fma forces vmcnt(0) each iteration,
//    ~200cy L1/L2-hit latency exposed per step with only ~9 waves/SIMD.
//  - This version: the address chain never depends on loaded data, so the
//    walk is restructured to a fixed trip count T (safe OVERcount: steps past
//    a_hi have weight exactly 0 -> fmaf(0,dv,acc) is a bit-exact no-op;
//    advancing an exhausted axis gives alpha>=a_hi by plane monotonicity)
//    with 4 rotating {w,addr,v} slots so 3-4 gathers stay in flight under
//    ~150cy of VALU.  Consume order == step order -> identical fma sequence.
// ---------------------------------------------------------------------------

#define NDIM   192
#define HW     (NDIM * NDIM)          // 36864
#define NSUB   (HW / 2)               // 18432
#define NTILE  576                    // 8x8 detector tiles (24x24 of them)
#define NBATCH 2
#define NCHUNK 16
#define NVOX   (NDIM * NDIM * NDIM)   // 7077888
#define SDRF   300.0f
#define RBLK   1728                   // reduce blocks: 1728*256*4 f4 == NVOX/4
#define NBLKX  (NSUB / 256)           // 72 ray blocks per (chunk,batch)

// ws layout (bytes):
//   [0..12)                      final {smin, rmin, rmax}
//   [16 .. 16+4*NSUB)            list (tile-ordered selected pixels)
//   [16+4*NSUB .. +4*3*RBLK)     block partials smin[RBLK],rmin[RBLK],rmax[RBLK]
#define WS_LIST_OFF 16
#define WS_PART_OFF (WS_LIST_OFF + 4 * NSUB)

// --------------------------- reduction stage 1 -----------------------------
// soft_min over (-800, 350]; rmin/rmax over v > -800 (BAM==1 -> identity).
// Each block stores 3 partials to DISTINCT slots (no atomics).
__global__ __launch_bounds__(256) void reduce_kernel(
    const float* __restrict__ vol, float* __restrict__ parts) {
    const int tid = blockIdx.x * 256 + threadIdx.x;
    const float4* __restrict__ v4 = (const float4*)vol;
    const int S = RBLK * 256;         // 442368

    float4 r0 = v4[tid + 0 * S];
    float4 r1 = v4[tid + 1 * S];
    float4 r2 = v4[tid + 2 * S];
    float4 r3 = v4[tid + 3 * S];

    float smin = FLT_MAX, rmin = FLT_MAX, rmax = -FLT_MAX;
    float4 rr[4] = {r0, r1, r2, r3};
#pragma unroll
    for (int k = 0; k < 4; ++k) {
        float xs[4] = {rr[k].x, rr[k].y, rr[k].z, rr[k].w};
#pragma unroll
        for (int j = 0; j < 4; ++j) {
            float x = xs[j];
            bool in = (x > -800.0f);
            rmin = fminf(rmin, in ? x : FLT_MAX);
            rmax = fmaxf(rmax, in ? x : -FLT_MAX);
            smin = fminf(smin, (in && x <= 350.0f) ? x : FLT_MAX);
        }
    }
#pragma unroll
    for (int off = 32; off > 0; off >>= 1) {
        smin = fminf(smin, __shfl_down(smin, off));
        rmin = fminf(rmin, __shfl_down(rmin, off));
        rmax = fmaxf(rmax, __shfl_down(rmax, off));
    }
    __shared__ float sm[4], rm[4], rx[4];
    int w = threadIdx.x >> 6;
    if ((threadIdx.x & 63) == 0) { sm[w] = smin; rm[w] = rmin; rx[w] = rmax; }
    __syncthreads();
    if (threadIdx.x == 0) {
        parts[blockIdx.x] =
            fminf(fminf(sm[0], sm[1]), fminf(sm[2], sm[3]));
        parts[RBLK + blockIdx.x] =
            fminf(fminf(rm[0], rm[1]), fminf(rm[2], rm[3]));
        parts[2 * RBLK + blockIdx.x] =
            fmaxf(fmaxf(rx[0], rx[1]), fmaxf(rx[2], rx[3]));
    }
}

// --------------------------- fused prep (ONE block) ------------------------
// Phase 1: final reduce of 3x1728 partials -> ws[0..2]
// Phase 2: zero LDS bitmask (36864 bits = 1152 u32)
// Phase 3: set bits from subsample_idx (LDS atomicOr)
// Phase 4: per-tile counts.  Tile t: ti=t/24, tj=t%24.  Pixel (pi, tj*8+j)
//          has bitmask BYTE index pi*24+tj, bit j  (byte-aligned columns!)
// Phase 5: Hillis-Steele exclusive scan over 576 counts
// Phase 6: emit list, row-major within tile == identical order to old emit.
__global__ __launch_bounds__(1024) void prep_kernel(
    const float* __restrict__ parts, const int* __restrict__ sidx,
    float* __restrict__ ws, int* __restrict__ list) {
    __shared__ unsigned int bits[HW / 32];   // 1152 u32 = 4608 B
    __shared__ int cnts[NTILE];
    __shared__ float red0[16], red1[16], red2[16];

    const int tid = threadIdx.x;

    // ---- phase 1: final reduce (strided over 1728 partials) ----
    float smin = FLT_MAX, rmin = FLT_MAX, rmax = -FLT_MAX;
    for (int i = tid; i < RBLK; i += 1024) {
        smin = fminf(smin, parts[i]);
        rmin = fminf(rmin, parts[RBLK + i]);
        rmax = fmaxf(rmax, parts[2 * RBLK + i]);
    }
#pragma unroll
    for (int off = 32; off > 0; off >>= 1) {
        smin = fminf(smin, __shfl_down(smin, off));
        rmin = fminf(rmin, __shfl_down(rmin, off));
        rmax = fmaxf(rmax, __shfl_down(rmax, off));
    }
    int w = tid >> 6;                  // 16 waves
    if ((tid & 63) == 0) { red0[w] = smin; red1[w] = rmin; red2[w] = rmax; }

    // ---- phase 2: zero bitmask (also covers the red[] sync) ----
    for (int i = tid; i < HW / 32; i += 1024) bits[i] = 0u;
    __syncthreads();
    if (tid == 0) {
        float a = FLT_MAX, b = FLT_MAX, c = -FLT_MAX;
#pragma unroll
        for (int k = 0; k < 16; ++k) {
            a = fminf(a, red0[k]);
            b = fminf(b, red1[k]);
            c = fmaxf(c, red2[k]);
        }
        ws[0] = a; ws[1] = b; ws[2] = c;
    }

    // ---- phase 3: set bits ----
    for (int i = tid; i < NSUB; i += 1024) {
        int p = sidx[i];
        atomicOr(&bits[p >> 5], 1u << (p & 31));
    }
    __syncthreads();

    // ---- phase 4: per-tile counts via byte popcounts ----
    const unsigned char* bb = (const unsigned char*)bits;
    int myc = 0;
    int ti = tid / 24, tj = tid % 24;  // valid when tid < NTILE
    if (tid < NTILE) {
#pragma unroll
        for (int r = 0; r < 8; ++r)
            myc += __popc((int)bb[(ti * 8 + r) * 24 + tj]);
        cnts[tid] = myc;
    }
    __syncthreads();

    // ---- phase 5: inclusive scan -> exclusive offset in register ----
    for (int off = 1; off < NTILE; off <<= 1) {
        int v = 0, u = 0;
        if (tid < NTILE) {
            v = cnts[tid];
            if (tid >= off) u = cnts[tid - off];
        }
        __syncthreads();
        if (tid < NTILE) cnts[tid] = v + u;
        __syncthreads();
    }

    // ---- phase 6: emit (row-major within tile; same order as old emit) ----
    if (tid < NTILE) {
        int o = cnts[tid] - myc;       // exclusive prefix
#pragma unroll
        for (int r = 0; r < 8; ++r) {
            int pibase = (ti * 8 + r) * NDIM + tj * 8;
            unsigned int m = (unsigned int)bb[(ti * 8 + r) * 24 + tj];
            while (m) {
                int j = __ffs(m) - 1;
                m &= m - 1u;
                list[o++] = pibase + j;
            }
        }
    }
}

// --------------------------- axis iterator init ----------------------------
// First plane index (walking toward increasing alpha) whose
// alpha = (i - s)/d is STRICTLY greater than a_lo.  Exact divides (once).
__device__ __forceinline__ void init_axis(float s, float d, float a_lo,
                                          int& i, int& st, float& na) {
    if (d > 0.0f) {
        st = 1;
        float f = s + a_lo * d;
        int ii = (int)floorf(f) + 1;
        ii = max(0, min(ii, NDIM + 1));
        while (ii <= NDIM && ((float)ii - s) / d <= a_lo) ++ii;
        while (ii > 0 && ((float)(ii - 1) - s) / d > a_lo) --ii;
        i  = ii;
        na = (ii <= NDIM) ? ((float)ii - s) / d : FLT_MAX;
    } else {
        st = -1;
        float f = s + a_lo * d;
        int ii = (int)ceilf(f) - 1;
        ii = max(-1, min(ii, NDIM));
        while (ii >= 0 && ((float)ii - s) / d <= a_lo) --ii;
        while (ii < NDIM && ((float)(ii + 1) - s) / d > a_lo) ++ii;
        i  = ii;
        na = (ii >= 0) ? ((float)ii - s) / d : FLT_MAX;
    }
}

// --------------------------- ray kernel ------------------------------------
// grid = (NSUB/256, NCHUNK, NBATCH), block = 256 (4 waves).
// Wave = 64 consecutive list entries (compact detector patches).
// Fixed-trip branch-free walk: T is a safe OVERcount of segment count; pad
// steps carry weight 0 exactly (alphas are monotone per axis, so once
// cur==a_hi every further a2==a_hi -> w==0; fmaf(0,dv,acc)==acc bitwise).
// Depth-4 rotating {w,addr,v} pipeline keeps 3-4 gathers in flight.
__global__ __launch_bounds__(256) void ray_kernel(
    const float* __restrict__ vol, const float* __restrict__ rot,
    const float* __restrict__ trans, const float* __restrict__ wsc,
    const int* __restrict__ list, float* __restrict__ out) {
    const int c = blockIdx.y;
    const int b = blockIdx.z;

    const int n = blockIdx.x * 256 + threadIdx.x;
    const int p  = list[n];
    const int pi = p / NDIM;
    const int pj = p % NDIM;

    // density normalization constants
    float smin = wsc[0];
    float rmin = wsc[1];
    float rmax = wsc[2];
    float dmin = fminf(smin, rmin);
    float dmax = fmaxf(smin, rmax);
    float scale = 1.0f / (dmax - dmin);

    // rotation R = Rz(r0) @ Ry(r1) @ Rx(r2)
    float rz = rot[b * 3 + 0], ry = rot[b * 3 + 1], rx = rot[b * 3 + 2];
    float cz = cosf(rz), sz = sinf(rz);
    float cy = cosf(ry), sy = sinf(ry);
    float cx = cosf(rx), sx = sinf(rx);
    float R00 = cz * cy;
    float R01 = cz * sy * sx - sz * cx;
    float R02 = sz * sx + cz * sy * cx;
    float R10 = sz * cy;
    float R11 = cz * cx + sz * sy * sx;
    float R12 = sz * sy * cx - cz * sx;
    float R20 = -sy;
    float R21 = cy * sx;
    float R22 = cy * cx;
    float tx = trans[b * 3 + 0] + 96.0f;
    float ty = trans[b * 3 + 1] + 96.0f;
    float tz = trans[b * 3 + 2] + 96.0f;

    float srcx = R02 * SDRF + tx;
    float srcy = R12 * SDRF + ty;
    float srcz = R22 * SDRF + tz;
    float gx = ((float)pj - 95.5f) * 2.0f;
    float gy = ((float)pi - 95.5f) * 2.0f;
    float tgx = R00 * gx + R01 * gy + R02 * (-SDRF) + tx;
    float tgy = R10 * gx + R11 * gy + R12 * (-SDRF) + ty;
    float tgz = R20 * gx + R21 * gy + R22 * (-SDRF) + tz;

    float sdx = tgx - srcx, sdy = tgy - srcy, sdz = tgz - srcz;
    float dsx = (sdx == 0.0f) ? 1e-9f : sdx;
    float dsy = (sdy == 0.0f) ? 1e-9f : sdy;
    float dsz = (sdz == 0.0f) ? 1e-9f : sdz;

    float af0 = (0.0f - srcx) / dsx, al0 = (192.0f - srcx) / dsx;
    float af1 = (0.0f - srcy) / dsy, al1 = (192.0f - srcy) / dsy;
    float af2 = (0.0f - srcz) / dsz, al2 = (192.0f - srcz) / dsz;
    float amin = fmaxf(fmaxf(fminf(af0, al0), fminf(af1, al1)), fminf(af2, al2));
    amin = fmaxf(amin, 0.0f);
    float amax = fminf(fminf(fmaxf(af0, al0), fmaxf(af1, al1)), fmaxf(af2, al2));
    amax = fminf(amax, 1.0f);
    amax = fmaxf(amax, amin);
    float ray_len = sqrtf(sdx * sdx + sdy * sdy + sdz * sdz);

    // alpha sub-interval of this chunk
    float span = amax - amin;
    float a_lo = amin + span * ((float)c / (float)NCHUNK);
    float a_hi = (c == NCHUNK - 1) ? amax
                                   : amin + span * ((float)(c + 1) / (float)NCHUNK);

    int i0, i1, i2, st0, st1, st2;
    float na0, na1, na2;
    init_axis(srcx, dsx, a_lo, i0, st0, na0);
    init_axis(srcy, dsy, a_lo, i1, st1, na1);
    init_axis(srcz, dsz, a_lo, i2, st2, na2);

    // reciprocals (IEEE divide once per thread) and float-index trackers
    float r0 = 1.0f / dsx, r1 = 1.0f / dsy, r2 = 1.0f / dsz;
    float fi0 = (float)i0, fi1 = (float)i1, fi2 = (float)i2;
    float fs0 = (float)st0, fs1 = (float)st1, fs2 = (float)st2;

    // Safe UPPER bound on segment count: crossings in [na, a_hi) per axis
    // are spaced 1/|d| apart -> count <= (a_hi-na)*|d| + 1; +2 covers float
    // slop.  Overcount is harmless (w==0 pad steps), undercount would drop
    // tail segments -> margins matter.
    int T = 1;
    if (na0 < a_hi) T += (int)((a_hi - na0) * fabsf(dsx)) + 2;
    if (na1 < a_hi) T += (int)((a_hi - na1) * fabsf(dsy)) + 2;
    if (na2 < a_hi) T += (int)((a_hi - na2) * fabsf(dsz)) + 2;

    float cur = a_lo;
    float acc = 0.0f;                 // sum of step * raw_density

    // One Siddon step: computes this segment's (weight, voxel addr) and
    // advances the crossing state.  Pure VALU; no dependence on loads.
    auto ADV = [&](float& wseg, int& addr) {
        float an = fminf(fminf(na0, na1), na2);
        float ae = fminf(an, a_hi);
        wseg = ae - cur;
        float mid = 0.5f * (cur + ae);
        float px = fmaf(mid, sdx, srcx);
        float py = fmaf(mid, sdy, srcy);
        float pz = fmaf(mid, sdz, srcz);
        int ix = min(max((int)px, 0), NDIM - 1);
        int iy = min(max((int)py, 0), NDIM - 1);
        int iz = min(max((int)pz, 0), NDIM - 1);
        addr = (NDIM - 1) * HW - ix * HW + iy * NDIM + iz;  // flip axis 0
        cur = ae;
        bool c0 = (na0 == an), c1 = (na1 == an), c2 = (na2 == an);
        float nf0 = fi0 + fs0, nf1 = fi1 + fs1, nf2 = fi2 + fs2;
        float nn0 = (nf0 - srcx) * r0;
        float nn1 = (nf1 - srcy) * r1;
        float nn2 = (nf2 - srcz) * r2;
        fi0 = c0 ? nf0 : fi0;  na0 = c0 ? nn0 : na0;
        fi1 = c1 ? nf1 : fi1;  na1 = c1 ? nn1 : na1;
        fi2 = c2 ? nf2 : fi2;  na2 = c2 ? nn2 : na2;
    };

    // Depth-4 software pipeline: slots consumed in step order (identical fma
    // sequence to the serial loop); 3-4 loads in flight at all times.
    float w0s, w1s, w2s, w3s;
    int   ad0, ad1, ad2, ad3;
    float v0, v1, v2, v3;
    ADV(w0s, ad0); v0 = vol[ad0];
    ADV(w1s, ad1); v1 = vol[ad1];
    ADV(w2s, ad2); v2 = vol[ad2];
    ADV(w3s, ad3); v3 = vol[ad3];
    for (int s = 0; s < T; s += 4) {
        float dv0 = (v0 <= -800.0f) ? smin : v0;
        acc = fmaf(w0s, dv0, acc);
        ADV(w0s, ad0); v0 = vol[ad0];
        float dv1 = (v1 <= -800.0f) ? smin : v1;
        acc = fmaf(w1s, dv1, acc);
        ADV(w1s, ad1); v1 = vol[ad1];
        float dv2 = (v2 <= -800.0f) ? smin : v2;
        acc = fmaf(w2s, dv2, acc);
        ADV(w2s, ad2); v2 = vol[ad2];
        float dv3 = (v3 <= -800.0f) ? smin : v3;
        acc = fmaf(w3s, dv3, acc);
        ADV(w3s, ad3); v3 = vol[ad3];
    }
    // 4 slots remain in flight at exit; their step numbers exceed T >= real
    // segment count, so each has w == 0 -> dropping them is exact.

    // sum step*(dv - dmin)*scale == scale*(acc - dmin*(a_hi - a_lo))
    float res = (acc - dmin * (a_hi - a_lo)) * scale * ray_len;
    atomicAdd(&out[b * HW + p], res);
}

// --------------------------- launch ----------------------------------------
extern "C" void kernel_launch(void* const* d_in, const int* in_sizes, int n_in,
                              void* d_out, int out_size, void* d_ws,
                              size_t ws_size, hipStream_t stream) {
    const float* vol   = (const float*)d_in[0];
    const float* rot   = (const float*)d_in[1];
    const float* trans = (const float*)d_in[2];
    const int*   sidx  = (const int*)d_in[3];
    float* out = (float*)d_out;

    float* wsf   = (float*)d_ws;
    int*   list  = (int*)((unsigned char*)d_ws + WS_LIST_OFF);
    float* parts = (float*)((unsigned char*)d_ws + WS_PART_OFF);

    hipMemsetAsync(d_out, 0, (size_t)out_size * sizeof(float), stream);

    reduce_kernel<<<RBLK, 256, 0, stream>>>(vol, parts);
    prep_kernel<<<1, 1024, 0, stream>>>(parts, sidx, wsf, list);
    dim3 rgrid(NBLKX, NCHUNK, NBATCH);
    ray_kernel<<<rgrid, 256, 0, stream>>>(vol, rot, trans, wsf, list, out);
}